// Round 2
// baseline (804.905 us; speedup 1.0000x reference)
//
#include <hip/hip_runtime.h>
#include <hip/hip_bf16.h>

#define EPSV 1e-12
#define RHASH 0.2

__device__ __forceinline__ int fmod2(double t) {
    // floor then mod 2 with numpy semantics (non-negative result)
    return (int)(((long long)floor(t)) & 1LL);
}

// ---------------------------------------------------------------------------
// setup: per-layer kernel hashes kh[], per-cin a-sums, query constants (double)
// dmeta layout: [0..2]=asum1, [3..18]=asum2, [19..38]=asum3, [39]=qc1,[40]=qc2,[41]=qc3
// imeta layout: [0..15]=kh1, [16..35]=kh2, [36..55]=kh3
// ---------------------------------------------------------------------------
__device__ void layer_setup(const float* W, const float* a, double cval,
                            int Co, int Ci, int* kh, double* asum, double* qc,
                            double* s_norm, float* Wbuf, float* abuf)
{
    const int t = threadIdx.x;
    const int D = Ci * 25;
    for (int i = t; i < Co * D; i += 256) Wbuf[i] = W[i];
    for (int i = t; i < D + 5; i += 256) abuf[i] = a[i];
    __syncthreads();
    if (t < Co) {
        double s = 0;
        for (int j = 0; j < D; ++j) { double w = (double)Wbuf[t * D + j]; s += w * w; }
        s_norm[t] = sqrt(s);
    }
    __syncthreads();
    if (t == 0) {
        double mx = 0;
        for (int i = 0; i < Co; ++i) mx = fmax(mx, s_norm[i]);
        s_norm[23] = 1.0 / (mx + EPSV);
    }
    __syncthreads();
    double scale = s_norm[23];
    if (t < Co) {
        double dp = 0;
        for (int j = 0; j < D; ++j) dp += (double)Wbuf[t * D + j] * (double)abuf[j];
        dp *= scale;
        double n = s_norm[t] * scale;
        double p = n * n;                       // n^2, n^4, n^8, n^16, n^32
        for (int m = 0; m < 5; ++m) { dp += p * (double)abuf[D + m]; p *= p; }
        kh[t] = fmod2((dp + cval) / RHASH);
    }
    if (t >= 64 && t < 64 + Ci) {
        int c = t - 64;
        double s = 0;
        for (int j = 0; j < 25; ++j) s += (double)abuf[c * 25 + j];
        asum[c] = s;
    }
    if (t == 128) {
        double s = 0;
        for (int m = 0; m < 5; ++m) s += (double)abuf[D + m];
        *qc = 0.5 * s + cval;
    }
    __syncthreads();
}

__global__ __launch_bounds__(256) void setup_kernel(
    const float* W1, const float* a1, const float* c1,
    const float* W2, const float* a2, const float* c2,
    const float* W3, const float* a3, const float* c3,
    double* dmeta, int* imeta)
{
    __shared__ float Wbuf[10000];
    __shared__ float abuf[512];
    __shared__ double s_norm[24];
    layer_setup(W1, a1, (double)c1[0], 16, 3,  imeta + 0,  dmeta + 0,  dmeta + 39, s_norm, Wbuf, abuf);
    layer_setup(W2, a2, (double)c2[0], 20, 16, imeta + 16, dmeta + 3,  dmeta + 40, s_norm, Wbuf, abuf);
    layer_setup(W3, a3, (double)c3[0], 20, 20, imeta + 36, dmeta + 19, dmeta + 41, s_norm, Wbuf, abuf);
}

// ---------------------------------------------------------------------------
// weight repack: fp32, rows of 5 padded to 8 (conv1/conv2) or 6 (conv3)
// Wp1: [16][15][8]=1920, Wp2: [20][80][8]=12800, Wp3: [20][100][6]=12000
// ---------------------------------------------------------------------------
__global__ __launch_bounds__(256) void pack_kernel(const float* W1, const float* W2, const float* W3,
                                                   float* Wp1, float* Wp2, float* Wp3)
{
    int i = blockIdx.x * 256 + threadIdx.x;
    if (i < 1920) {
        int co = i / 120, r = i % 120, cik = r / 8, j = r % 8;
        Wp1[i] = (j < 5) ? W1[co * 75 + cik * 5 + j] : 0.f;
    } else if (i < 1920 + 12800) {
        int k = i - 1920;
        int co = k / 640, r = k % 640, cik = r / 8, j = r % 8;
        Wp2[k] = (j < 5) ? W2[co * 400 + cik * 5 + j] : 0.f;
    } else if (i < 1920 + 12800 + 12000) {
        int k = i - 14720;
        int co = k / 600, r = k % 600, cik = r / 6, j = r % 6;
        Wp3[k] = (j < 5) ? W3[co * 500 + cik * 5 + j] : 0.f;
    }
}

// ---------------------------------------------------------------------------
// conv1: x[4096,3,32,32] f32 -> h1[4096,16,16,16] f32 (conv+bias+relu+mask+pool)
// one block per sample; thread = 1 pooled pos (16x16) x all 16 co
// ---------------------------------------------------------------------------
__global__ __launch_bounds__(256) void conv1_kernel(
    const float* __restrict__ x, const float* __restrict__ Wp1,
    const float* __restrict__ b1, const int* __restrict__ kh1,
    const double* __restrict__ dmeta, float* __restrict__ h1)
{
    __shared__ float xs[3][36][36];
    __shared__ float Ws[16][120];      // [co][(ci*5+ky)*8 + j]
    __shared__ double red[256];
    __shared__ double s_csum[3];
    __shared__ float s_mask[16];
    __shared__ float s_bias[16];

    const int b = blockIdx.x, t = threadIdx.x;

    for (int i = t; i < 3 * 36 * 36; i += 256) (&xs[0][0][0])[i] = 0.f;
    for (int i = t; i < 1920; i += 256) (&Ws[0][0])[i] = Wp1[i];
    if (t < 16) s_bias[t] = b1[t];
    __syncthreads();
    const float* xb = x + (size_t)b * 3072;
    const float2* xb2 = (const float2*)xb;
    for (int i = t; i < 1536; i += 256) {
        int idx = i * 2;
        int c = idx >> 10, rem = idx & 1023, y = rem >> 5, xx = rem & 31;
        *(float2*)&xs[c][y + 2][xx + 2] = xb2[i];
    }
    __syncthreads();
    // channel sums (3 x 1024)
    for (int c = 0; c < 3; ++c) {
        double p = 0;
        for (int i = t; i < 1024; i += 256) p += (double)xs[c][(i >> 5) + 2][(i & 31) + 2];
        red[t] = p; __syncthreads();
        for (int s = 128; s > 0; s >>= 1) { if (t < s) red[t] += red[t + s]; __syncthreads(); }
        if (t == 0) s_csum[c] = red[0];
        __syncthreads();
    }
    if (t == 0) {
        double dp = 0, nn = 0;
        for (int c = 0; c < 3; ++c) {
            double cm = s_csum[c] * (1.0 / 1024.0);
            dp += cm * dmeta[c]; nn += cm * cm;
        }
        double tt = (dp / (5.0 * sqrt(nn) + EPSV) + dmeta[39]) / RHASH;
        int qh = fmod2(tt);
        for (int co = 0; co < 16; ++co) s_mask[co] = (kh1[co] == qh) ? 1.f : 0.f;
    }
    __syncthreads();

    const int py = t >> 4, px = t & 15;
    const int y0 = 2 * py, x0 = 2 * px;     // padded coords
    float acc[16][4];
    #pragma unroll
    for (int c = 0; c < 16; ++c) {
        float bb = s_bias[c];
        acc[c][0] = bb; acc[c][1] = bb; acc[c][2] = bb; acc[c][3] = bb;
    }
    for (int ci = 0; ci < 3; ++ci) {
        #pragma unroll
        for (int ky = 0; ky < 5; ++ky) {
            float xr0[6], xr1[6];
            const float2* p0 = (const float2*)&xs[ci][y0 + ky][x0];
            const float2* p1 = (const float2*)&xs[ci][y0 + ky + 1][x0];
            float2 a0 = p0[0], a1v = p0[1], a2v = p0[2];
            float2 b0 = p1[0], b1v = p1[1], b2v = p1[2];
            xr0[0] = a0.x; xr0[1] = a0.y; xr0[2] = a1v.x; xr0[3] = a1v.y; xr0[4] = a2v.x; xr0[5] = a2v.y;
            xr1[0] = b0.x; xr1[1] = b0.y; xr1[2] = b1v.x; xr1[3] = b1v.y; xr1[4] = b2v.x; xr1[5] = b2v.y;
            #pragma unroll
            for (int c = 0; c < 16; ++c) {
                const float4* wp = (const float4*)&Ws[c][(ci * 5 + ky) * 8];
                float4 w0 = wp[0], w1 = wp[1];
                float w[5] = {w0.x, w0.y, w0.z, w0.w, w1.x};
                #pragma unroll
                for (int kx = 0; kx < 5; ++kx) {
                    acc[c][0] += w[kx] * xr0[kx];
                    acc[c][1] += w[kx] * xr0[kx + 1];
                    acc[c][2] += w[kx] * xr1[kx];
                    acc[c][3] += w[kx] * xr1[kx + 1];
                }
            }
        }
    }
    float* hb = h1 + (size_t)b * 4096;
    #pragma unroll
    for (int c = 0; c < 16; ++c) {
        float m = fmaxf(fmaxf(acc[c][0], acc[c][1]), fmaxf(acc[c][2], acc[c][3]));
        hb[c * 256 + t] = fmaxf(m, 0.f) * s_mask[c];
    }
}

// ---------------------------------------------------------------------------
// conv2: h1[4096,16,16,16] f32 -> h2[4096,20,8,8] f32
// thread = 1 pooled pos (8x8=64) x co-group of 5 (4 groups)
// ---------------------------------------------------------------------------
__global__ __launch_bounds__(256) void conv2_kernel(
    const float* __restrict__ h1, const float* __restrict__ Wp2,
    const float* __restrict__ b2, const int* __restrict__ kh2,
    const double* __restrict__ dmeta, float* __restrict__ h2)
{
    __shared__ float xs[16][20][20];
    __shared__ float Ws[20][640];      // [co][(ci*5+ky)*8 + j]
    __shared__ double red[256];
    __shared__ double s_csum[16];
    __shared__ float s_mask[20];
    __shared__ float s_bias[20];

    const int b = blockIdx.x, t = threadIdx.x;
    for (int i = t; i < 6400; i += 256) (&xs[0][0][0])[i] = 0.f;
    for (int i = t; i < 12800; i += 256) (&Ws[0][0])[i] = Wp2[i];
    if (t < 20) s_bias[t] = b2[t];
    __syncthreads();
    const float* xb = h1 + (size_t)b * 4096;
    const float2* xb2 = (const float2*)xb;
    for (int i = t; i < 2048; i += 256) {
        int idx = i * 2;
        int c = idx >> 8, rem = idx & 255, y = rem >> 4, xx = rem & 15;
        *(float2*)&xs[c][y + 2][xx + 2] = xb2[i];
    }
    __syncthreads();
    { // channel sums: 16 ch x 256, 16 threads per channel
        int c = t >> 4, lane = t & 15;
        double p = 0;
        for (int j = 0; j < 16; ++j) {
            int i = lane * 16 + j;
            p += (double)xs[c][(i >> 4) + 2][(i & 15) + 2];
        }
        red[t] = p;
    }
    __syncthreads();
    if (t < 16) { double s = 0; for (int j = 0; j < 16; ++j) s += red[t * 16 + j]; s_csum[t] = s; }
    __syncthreads();
    if (t == 0) {
        double dp = 0, nn = 0;
        for (int c = 0; c < 16; ++c) {
            double cm = s_csum[c] * (1.0 / 256.0);
            dp += cm * dmeta[3 + c]; nn += cm * cm;
        }
        double tt = (dp / (5.0 * sqrt(nn) + EPSV) + dmeta[40]) / RHASH;
        int qh = fmod2(tt);
        for (int co = 0; co < 20; ++co) s_mask[co] = (kh2[co] == qh) ? 1.f : 0.f;
    }
    __syncthreads();

    const int pos = t & 63, cog = t >> 6;
    const int py = pos >> 3, px = pos & 7;
    const int y0 = 2 * py, x0 = 2 * px;
    float acc[5][4];
    #pragma unroll
    for (int c = 0; c < 5; ++c) {
        float bb = s_bias[cog * 5 + c];
        acc[c][0] = bb; acc[c][1] = bb; acc[c][2] = bb; acc[c][3] = bb;
    }
    for (int ci = 0; ci < 16; ++ci) {
        #pragma unroll
        for (int ky = 0; ky < 5; ++ky) {
            float xr0[6], xr1[6];
            const float2* p0 = (const float2*)&xs[ci][y0 + ky][x0];
            const float2* p1 = (const float2*)&xs[ci][y0 + ky + 1][x0];
            float2 a0 = p0[0], a1v = p0[1], a2v = p0[2];
            float2 b0 = p1[0], b1v = p1[1], b2v = p1[2];
            xr0[0] = a0.x; xr0[1] = a0.y; xr0[2] = a1v.x; xr0[3] = a1v.y; xr0[4] = a2v.x; xr0[5] = a2v.y;
            xr1[0] = b0.x; xr1[1] = b0.y; xr1[2] = b1v.x; xr1[3] = b1v.y; xr1[4] = b2v.x; xr1[5] = b2v.y;
            #pragma unroll
            for (int c = 0; c < 5; ++c) {
                const float4* wp = (const float4*)&Ws[cog * 5 + c][(ci * 5 + ky) * 8];
                float4 w0 = wp[0], w1 = wp[1];
                float w[5] = {w0.x, w0.y, w0.z, w0.w, w1.x};
                #pragma unroll
                for (int kx = 0; kx < 5; ++kx) {
                    acc[c][0] += w[kx] * xr0[kx];
                    acc[c][1] += w[kx] * xr0[kx + 1];
                    acc[c][2] += w[kx] * xr1[kx];
                    acc[c][3] += w[kx] * xr1[kx + 1];
                }
            }
        }
    }
    float* ob = h2 + (size_t)b * 1280;
    #pragma unroll
    for (int c = 0; c < 5; ++c) {
        int co = cog * 5 + c;
        float m = fmaxf(fmaxf(acc[c][0], acc[c][1]), fmaxf(acc[c][2], acc[c][3]));
        ob[co * 64 + pos] = fmaxf(m, 0.f) * s_mask[co];
    }
}

// ---------------------------------------------------------------------------
// conv3 + final linear: h2[4096,20,8,8] f32 -> out[4096,10] f32
// conv part: 160 threads = 16 pos x 10 co-groups of 2
// ---------------------------------------------------------------------------
__global__ __launch_bounds__(256) void conv3_kernel(
    const float* __restrict__ h2, const float* __restrict__ Wp3,
    const float* __restrict__ b3, const int* __restrict__ kh3,
    const double* __restrict__ dmeta,
    const float* __restrict__ Wo, const float* __restrict__ bo,
    float* __restrict__ out)
{
    __shared__ float xs[20][12][12];
    __shared__ float Ws[20][600];      // [co][(ci*5+ky)*6 + j]
    __shared__ float Wos[10][320];
    __shared__ float flat[320];
    __shared__ double red[256];
    __shared__ double s_csum[20];
    __shared__ float s_mask[20];
    __shared__ float s_bias[20];

    const int b = blockIdx.x, t = threadIdx.x;
    for (int i = t; i < 2880; i += 256) (&xs[0][0][0])[i] = 0.f;
    for (int i = t; i < 12000; i += 256) (&Ws[0][0])[i] = Wp3[i];
    for (int i = t; i < 3200; i += 256) (&Wos[0][0])[i] = Wo[i];
    if (t < 20) s_bias[t] = b3[t];
    __syncthreads();
    const float* xb = h2 + (size_t)b * 1280;
    const float2* xb2 = (const float2*)xb;
    for (int i = t; i < 640; i += 256) {
        int idx = i * 2;
        int c = idx >> 6, rem = idx & 63, y = rem >> 3, xx = rem & 7;
        *(float2*)&xs[c][y + 2][xx + 2] = xb2[i];
    }
    __syncthreads();
    if (t < 160) { // channel sums: 20 ch x 64, 8 threads per channel
        int c = t >> 3, lane = t & 7;
        double p = 0;
        for (int j = 0; j < 8; ++j) {
            int i = lane * 8 + j;
            p += (double)xs[c][(i >> 3) + 2][(i & 7) + 2];
        }
        red[t] = p;
    }
    __syncthreads();
    if (t < 20) { double s = 0; for (int j = 0; j < 8; ++j) s += red[t * 8 + j]; s_csum[t] = s; }
    __syncthreads();
    if (t == 0) {
        double dp = 0, nn = 0;
        for (int c = 0; c < 20; ++c) {
            double cm = s_csum[c] * (1.0 / 64.0);
            dp += cm * dmeta[19 + c]; nn += cm * cm;
        }
        double tt = (dp / (5.0 * sqrt(nn) + EPSV) + dmeta[41]) / RHASH;
        int qh = fmod2(tt);
        for (int co = 0; co < 20; ++co) s_mask[co] = (kh3[co] == qh) ? 1.f : 0.f;
    }
    __syncthreads();

    if (t < 160) {
        const int pos = t & 15, cog = t >> 4;   // 10 groups x 2 co
        const int py = pos >> 2, px = pos & 3;
        const int y0 = 2 * py, x0 = 2 * px;
        float acc[2][4];
        #pragma unroll
        for (int c = 0; c < 2; ++c) {
            float bb = s_bias[cog * 2 + c];
            acc[c][0] = bb; acc[c][1] = bb; acc[c][2] = bb; acc[c][3] = bb;
        }
        for (int ci = 0; ci < 20; ++ci) {
            #pragma unroll
            for (int ky = 0; ky < 5; ++ky) {
                float xr0[6], xr1[6];
                const float2* p0 = (const float2*)&xs[ci][y0 + ky][x0];
                const float2* p1 = (const float2*)&xs[ci][y0 + ky + 1][x0];
                float2 a0 = p0[0], a1v = p0[1], a2v = p0[2];
                float2 b0 = p1[0], b1v = p1[1], b2v = p1[2];
                xr0[0] = a0.x; xr0[1] = a0.y; xr0[2] = a1v.x; xr0[3] = a1v.y; xr0[4] = a2v.x; xr0[5] = a2v.y;
                xr1[0] = b0.x; xr1[1] = b0.y; xr1[2] = b1v.x; xr1[3] = b1v.y; xr1[4] = b2v.x; xr1[5] = b2v.y;
                #pragma unroll
                for (int c = 0; c < 2; ++c) {
                    const float* wr = &Ws[cog * 2 + c][(ci * 5 + ky) * 6];
                    const float2* wp = (const float2*)wr;
                    float2 w01 = wp[0], w23 = wp[1];
                    float w4 = wr[4];
                    float w[5] = {w01.x, w01.y, w23.x, w23.y, w4};
                    #pragma unroll
                    for (int kx = 0; kx < 5; ++kx) {
                        acc[c][0] += w[kx] * xr0[kx];
                        acc[c][1] += w[kx] * xr0[kx + 1];
                        acc[c][2] += w[kx] * xr1[kx];
                        acc[c][3] += w[kx] * xr1[kx + 1];
                    }
                }
            }
        }
        #pragma unroll
        for (int c = 0; c < 2; ++c) {
            int co = cog * 2 + c;
            float m = fmaxf(fmaxf(acc[c][0], acc[c][1]), fmaxf(acc[c][2], acc[c][3]));
            flat[co * 16 + pos] = fmaxf(m, 0.f) * s_mask[co];
        }
    }
    __syncthreads();
    if (t < 10) {
        float a = bo[t];
        const float* wr = &Wos[t][0];
        for (int k = 0; k < 320; ++k) a += flat[k] * wr[k];
        out[(size_t)b * 10 + t] = a;
    }
}

// ---------------------------------------------------------------------------
extern "C" void kernel_launch(void* const* d_in, const int* in_sizes, int n_in,
                              void* d_out, int out_size, void* d_ws, size_t ws_size,
                              hipStream_t stream)
{
    const float* x  = (const float*)d_in[0];
    const float* W1 = (const float*)d_in[1];
    const float* b1 = (const float*)d_in[2];
    const float* a1 = (const float*)d_in[3];
    const float* c1 = (const float*)d_in[4];
    const float* W2 = (const float*)d_in[5];
    const float* b2 = (const float*)d_in[6];
    const float* a2 = (const float*)d_in[7];
    const float* c2 = (const float*)d_in[8];
    const float* W3 = (const float*)d_in[9];
    const float* b3 = (const float*)d_in[10];
    const float* a3 = (const float*)d_in[11];
    const float* c3 = (const float*)d_in[12];
    const float* Wo = (const float*)d_in[13];
    const float* bo = (const float*)d_in[14];
    float* out = (float*)d_out;

    const int B = in_sizes[0] / 3072;   // 4096

    float* h1  = (float*)d_ws;                       // B*4096 f32
    float* h2  = h1 + (size_t)B * 4096;              // B*1280 f32
    float* Wp1 = h2 + (size_t)B * 1280;              // 1920
    float* Wp2 = Wp1 + 1920;                         // 12800
    float* Wp3 = Wp2 + 12800;                        // 12000
    double* dmeta = (double*)(Wp3 + 12000);          // 42 doubles (8B aligned)
    int* imeta = (int*)(dmeta + 42);                 // 56 ints

    setup_kernel<<<1, 256, 0, stream>>>(W1, a1, c1, W2, a2, c2, W3, a3, c3, dmeta, imeta);
    pack_kernel<<<105, 256, 0, stream>>>(W1, W2, W3, Wp1, Wp2, Wp3);
    conv1_kernel<<<B, 256, 0, stream>>>(x, Wp1, b1, imeta, dmeta, h1);
    conv2_kernel<<<B, 256, 0, stream>>>(h1, Wp2, b2, imeta + 16, dmeta, h2);
    conv3_kernel<<<B, 256, 0, stream>>>(h2, Wp3, b3, imeta + 36, dmeta, Wo, bo, out);
}